// Round 2
// baseline (421.461 us; speedup 1.0000x reference)
//
#include <hip/hip_runtime.h>

#define B_  64
#define D_  4096
#define S_  128
#define N_  256
#define KC_ 4
#define KPB (D_ / KC_)     // 1024 K per kc slice
#define BK  64             // K per LDS chunk
#define NCH (KPB / BK)     // 16 chunks
#define RS  72             // LDS row stride (shorts): 64 data + 8 pad = 144 B = 9 granules (odd -> full bank coverage)
#define LDSBUF (N_ * RS)   // 18432 shorts = 36 KB per buffer
#define TILE_ (N_ * N_)

using short8   = __attribute__((ext_vector_type(8)))  short;
using floatx16 = __attribute__((ext_vector_type(16))) float;

// hardware packed f32->bf16 (RNE), 1 instr per pair
__device__ __forceinline__ unsigned int pk2(float lo, float hi) {
  unsigned int r;
  asm("v_cvt_pk_bf16_f32 %0, %1, %2" : "=v"(r) : "v"(lo), "v"(hi));
  return r;
}

// Row stride = 9 granules (odd) -> consecutive rows already spread across all
// 8 bank-groups (group = n mod 8). Only the 8-row alias (9*8 ≡ 0 mod 8) needs
// breaking: XOR granule with (n>>3)&3. (Previous (n&3) term forced n+(n&3) ≡ 0
// mod 2 -> even groups only -> 2x imbalance; removed.)
__device__ __forceinline__ int swz(int n, int g) {
  return n * RS + ((g ^ ((n >> 3) & 3)) << 3);
}

// One block computes the FULL 256x256 Gram tile for (kc, b): zero duplicate
// HBM/L3 delivery. 8 waves in a 4(row)x2(col) grid, each wave 64x128 ->
// acc[2][4]. Grid (KC_, B_) = 256 blocks = 1 block/CU, 2 waves/SIMD.
__global__ __launch_bounds__(512, 2) void k_gram(
    const float* __restrict__ src, const float* __restrict__ tgt,
    float* __restrict__ partial, float* __restrict__ tot,
    float* __restrict__ sq) {
  __shared__ unsigned short lds[2 * LDSBUF];  // 72 KB
  __shared__ float red[8];
  const int kc  = blockIdx.x;
  const int b   = blockIdx.y;
  const int tid = threadIdx.x;
  const int l   = tid & 63;
  const int w   = tid >> 6;            // wave 0..7
  const int wr  = w >> 1;              // 0..3 (64-row group)
  const int wc  = w & 1;               // 0..1 (128-col group)

  // staging: thread owns column n_s; batch A = granules {g, g+2},
  // batch B = {g+4, g+6}; 16 regs live per batch, both batches issued ahead.
  const int n_s = tid & 255;
  const int g   = tid >> 8;            // 0..1
  const float* colbase = (n_s < S_)
      ? (src + (size_t)b * D_ * S_ + n_s)
      : (tgt + (size_t)b * D_ * S_ + (n_s - S_));
  const float* pA = colbase + (size_t)kc * KPB * S_;

  float ld[16], ld2[16];
  floatx16 acc[2][4];
  #pragma unroll
  for (int i = 0; i < 2; i++)
    #pragma unroll
    for (int j = 0; j < 4; j++)
      #pragma unroll
      for (int r = 0; r < 16; r++) acc[i][j][r] = 0.f;

  const int lm   = l & 31;
  const int lk   = l >> 5;             // 0/1
  const int ar   = wr * 64 + lm;       // A rows (sub adds 32)
  const int bcol = wc * 128 + lm;      // B cols (sub adds 32/64/96)

  #define LOADH(arr, ch, gb)                                           \
    do {                                                               \
      const float* q = pA + (size_t)(ch) * BK * S_;                    \
      _Pragma("unroll")                                                \
      for (int j = 0; j < 8; j++) {                                    \
        arr[j]     = q[(size_t)(((gb)) * 8 + j) * S_];                 \
        arr[8 + j] = q[(size_t)(((gb) + 2) * 8 + j) * S_];             \
      }                                                                \
    } while (0)

  #define WRITEH(arr, buf, gb)                                         \
    do {                                                               \
      uint4 wa, wb;                                                    \
      wa.x = pk2(arr[0],  arr[1]);                                     \
      wa.y = pk2(arr[2],  arr[3]);                                     \
      wa.z = pk2(arr[4],  arr[5]);                                     \
      wa.w = pk2(arr[6],  arr[7]);                                     \
      wb.x = pk2(arr[8],  arr[9]);                                     \
      wb.y = pk2(arr[10], arr[11]);                                    \
      wb.z = pk2(arr[12], arr[13]);                                    \
      wb.w = pk2(arr[14], arr[15]);                                    \
      const int base_ = (buf) * LDSBUF;                                \
      *(uint4*)&lds[base_ + swz(n_s, (gb))]     = wa;                  \
      *(uint4*)&lds[base_ + swz(n_s, (gb) + 2)] = wb;                  \
    } while (0)

  #define MFMA4(buf, k0)                                               \
    do {                                                               \
      const unsigned short* L = &lds[(buf) * LDSBUF];                  \
      _Pragma("unroll")                                                \
      for (int ks = (k0); ks < (k0) + 2; ks++) {                       \
        const int gg = ks * 2 + lk;                                    \
        short8 a0 = *(const short8*)&L[swz(ar,        gg)];            \
        short8 a1 = *(const short8*)&L[swz(ar + 32,   gg)];            \
        short8 b0 = *(const short8*)&L[swz(bcol,      gg)];            \
        short8 b1 = *(const short8*)&L[swz(bcol + 32, gg)];            \
        short8 b2 = *(const short8*)&L[swz(bcol + 64, gg)];            \
        short8 b3 = *(const short8*)&L[swz(bcol + 96, gg)];            \
        acc[0][0] = __builtin_amdgcn_mfma_f32_32x32x16_bf16(a0, b0, acc[0][0], 0, 0, 0); \
        acc[0][1] = __builtin_amdgcn_mfma_f32_32x32x16_bf16(a0, b1, acc[0][1], 0, 0, 0); \
        acc[0][2] = __builtin_amdgcn_mfma_f32_32x32x16_bf16(a0, b2, acc[0][2], 0, 0, 0); \
        acc[0][3] = __builtin_amdgcn_mfma_f32_32x32x16_bf16(a0, b3, acc[0][3], 0, 0, 0); \
        acc[1][0] = __builtin_amdgcn_mfma_f32_32x32x16_bf16(a1, b0, acc[1][0], 0, 0, 0); \
        acc[1][1] = __builtin_amdgcn_mfma_f32_32x32x16_bf16(a1, b1, acc[1][1], 0, 0, 0); \
        acc[1][2] = __builtin_amdgcn_mfma_f32_32x32x16_bf16(a1, b2, acc[1][2], 0, 0, 0); \
        acc[1][3] = __builtin_amdgcn_mfma_f32_32x32x16_bf16(a1, b3, acc[1][3], 0, 0, 0); \
      }                                                                \
    } while (0)

  // prologue: stage chunk 0 (both batches in flight before conversion)
  LOADH(ld,  0, g);
  LOADH(ld2, 0, g + 4);
  WRITEH(ld,  0, g);
  WRITEH(ld2, 0, g + 4);
  __syncthreads();
  // steady state: both 16-load batches issued before any MFMA/vmcnt wait ->
  // 32 loads (8 KB/wave) in flight; WRITEH(ld) waits only the first 16.
  for (int ch = 0; ch < NCH - 1; ch++) {
    LOADH(ld,  ch + 1, g);
    LOADH(ld2, ch + 1, g + 4);
    MFMA4(ch & 1, 0);
    WRITEH(ld, (ch + 1) & 1, g);
    MFMA4(ch & 1, 2);
    WRITEH(ld2, (ch + 1) & 1, g + 4);
    __syncthreads();
  }
  MFMA4((NCH - 1) & 1, 0);
  MFMA4((NCH - 1) & 1, 2);

  // ---- epilogue: store full tile (plain stores) ----
  float* gb = partial + ((size_t)kc * B_ + b) * TILE_;
  #pragma unroll
  for (int i = 0; i < 2; i++)
    #pragma unroll
    for (int j = 0; j < 4; j++)
      #pragma unroll
      for (int r = 0; r < 16; r++) {
        const int row = (r & 3) + 8 * (r >> 2) + 4 * lk;  // verified C/D layout
        const int nr  = wr * 64 + i * 32 + row;
        const int nc  = wc * 128 + j * 32 + (l & 31);
        gb[nr * N_ + nc] = acc[i][j][r];
      }

  // ---- tot[b]: block-level sum of this tile ----
  float s = 0.f;
  #pragma unroll
  for (int i = 0; i < 2; i++)
    #pragma unroll
    for (int j = 0; j < 4; j++)
      #pragma unroll
      for (int r = 0; r < 16; r++) s += acc[i][j][r];
  for (int off = 32; off; off >>= 1) s += __shfl_down(s, off);
  if (l == 0) red[w] = s;
  __syncthreads();
  if (tid == 0) {
    float T = red[0] + red[1] + red[2] + red[3]
            + red[4] + red[5] + red[6] + red[7];
    atomicAdd(&tot[b], T);
  }

  // ---- sq[b][c]: diagonal contributions ----
  // wave (wr,wc) holds the diagonal iff wc == wr>>1; diagonal j-block = (wr&1)*2 + i.
  if (wc == (wr >> 1) && lk == ((l >> 2) & 1)) {
    const int c = l & 31;
    const int r = (c >> 3) * 4 + (c & 3);   // reg holding row==col
    const int basej = (wr & 1) * 2;
    #pragma unroll
    for (int i = 0; i < 2; i++)
      atomicAdd(&sq[b * N_ + wr * 64 + i * 32 + c], acc[i][basej + i][r]);
  }
  #undef LOADH
  #undef WRITEH
  #undef MFMA4
}

// Sum 4 partials inline, reconstruct L2, 5-kernel exp with quadrant signs.
// 512 blocks (8 row-chunks x 64 batches, 2 blocks/CU), float4 loads.
__global__ __launch_bounds__(512, 4) void k_exp(
    const float* __restrict__ partial, const float* __restrict__ tot,
    const float* __restrict__ sq, float* __restrict__ out) {
  __shared__ float sqs[N_];
  __shared__ float red[8];
  __shared__ float bws;
  const int rc = blockIdx.x;           // 0..7: 32-row chunk
  const int b  = blockIdx.y;
  const int t  = threadIdx.x;          // 512
  const int cg = t & 63;               // col group (x4)
  const int rg = t >> 6;               // 0..7: 4-row group

  if (t < N_) sqs[t] = sq[b * N_ + t];
  __syncthreads();
  if (t < N_) {
    float v = sqs[t];
    for (int off = 32; off; off >>= 1) v += __shfl_down(v, off);
    if ((t & 63) == 0) red[t >> 6] = v;
  }
  __syncthreads();
  if (t == 0) {
    float ssq = red[0] + red[1] + red[2] + red[3];
    float SL2 = 2.f * (float)N_ * ssq - 2.f * tot[b];
    bws = SL2 / (float)(N_ * N_ - N_) * 0.25f;  // / kernel_mul^(num//2)
  }
  __syncthreads();

  const float bwv = bws;
  float nb[5];
  #pragma unroll
  for (int k = 0; k < 5; k++)
    nb[k] = -1.4426950408889634f / (bwv * (float)(1 << k));

  const int c4 = cg * 4;
  const float4 sqc = *(const float4*)&sqs[c4];
  const float sgn = ((rc < 4) == (cg < 32)) ? 1.f : -1.f;  // quadrant sign
  const float* p0 = partial + (size_t)b * TILE_;

  float accv = 0.f;
  #pragma unroll
  for (int r = 0; r < 4; r++) {
    const int row = rc * 32 + rg * 4 + r;
    const float4 g0 = *(const float4*)&p0[row * N_ + c4];
    const float4 g1 = *(const float4*)&p0[(size_t)1 * B_ * TILE_ + row * N_ + c4];
    const float4 g2 = *(const float4*)&p0[(size_t)2 * B_ * TILE_ + row * N_ + c4];
    const float4 g3 = *(const float4*)&p0[(size_t)3 * B_ * TILE_ + row * N_ + c4];
    const float sr = sqs[row];
    float4 L2;
    L2.x = sr + sqc.x - 2.f * (g0.x + g1.x + g2.x + g3.x);
    L2.y = sr + sqc.y - 2.f * (g0.y + g1.y + g2.y + g3.y);
    L2.z = sr + sqc.z - 2.f * (g0.z + g1.z + g2.z + g3.z);
    L2.w = sr + sqc.w - 2.f * (g0.w + g1.w + g2.w + g3.w);
    #pragma unroll
    for (int k = 0; k < 5; k++) {
      accv += exp2f(L2.x * nb[k]) + exp2f(L2.y * nb[k])
            + exp2f(L2.z * nb[k]) + exp2f(L2.w * nb[k]);
    }
  }
  accv *= sgn;
  for (int off = 32; off; off >>= 1) accv += __shfl_down(accv, off);
  __syncthreads();  // red[] reuse safe (t==0 consumed it before bws barrier)
  if ((t & 63) == 0) red[t >> 6] = accv;
  __syncthreads();
  if (t == 0) {
    float s2 = red[0] + red[1] + red[2] + red[3]
             + red[4] + red[5] + red[6] + red[7];
    atomicAdd(out, s2 * (1.0f / (64.f * 16384.f)));  // / (B * S*S)
  }
}

extern "C" void kernel_launch(void* const* d_in, const int* in_sizes, int n_in,
                              void* d_out, int out_size, void* d_ws, size_t ws_size,
                              hipStream_t stream) {
  const float* src = (const float*)d_in[0];
  const float* tgt = (const float*)d_in[1];
  const size_t partial_bytes = (size_t)KC_ * B_ * TILE_ * sizeof(float);  // 67 MB
  float* partial = (float*)d_ws;
  float* tot     = (float*)((char*)d_ws + partial_bytes);         // 64 floats
  float* sq      = tot + B_;                                      // 64*256 floats
  hipMemsetAsync(tot, 0, (B_ + B_ * N_) * sizeof(float), stream);
  hipMemsetAsync(d_out, 0, sizeof(float), stream);
  k_gram<<<dim3(KC_, B_), 512, 0, stream>>>(src, tgt, partial, tot, sq);
  k_exp<<<dim3(8, B_), 512, 0, stream>>>(partial, tot, sq, (float*)d_out);
}

// Round 4
// 309.868 us; speedup vs baseline: 1.3601x; 1.3601x over previous
//
#include <hip/hip_runtime.h>

#define B_  64
#define D_  4096
#define S_  128
#define N_  256
#define KC_ 4
#define KPB (D_ / KC_)     // 1024 K per kc slice
#define BK  64             // K per LDS chunk
#define NCH (KPB / BK)     // 16 chunks
#define RS  72             // LDS row stride (shorts): 64 data + 8 pad = 9 granules (odd -> full bank coverage)
#define LDSBUF (N_ * RS)   // 18432 shorts = 36 KB per buffer
#define TILE_ (N_ * N_)

using short8   = __attribute__((ext_vector_type(8)))  short;
using floatx16 = __attribute__((ext_vector_type(16))) float;

// hardware packed f32->bf16 (RNE), 1 instr per pair
__device__ __forceinline__ unsigned int pk2(float lo, float hi) {
  unsigned int r;
  asm("v_cvt_pk_bf16_f32 %0, %1, %2" : "=v"(r) : "v"(lo), "v"(hi));
  return r;
}

// Row stride = 9 granules (odd): group(n,g) = (9n + g') mod 8 = (n + g') mod 8.
// Consecutive rows spread over all 8 bank-groups; XOR with (n>>3)&3 breaks the
// 8-row alias. Enumeration: any 32-consecutive-row, fixed-g access hits each
// 4-bank group exactly 4x (even), and a 64-row wave write hits each 8x.
__device__ __forceinline__ int swz(int n, int g) {
  return n * RS + ((g ^ ((n >> 3) & 3)) << 3);
}

// One block computes the FULL 256x256 Gram tile for (kc, b): zero duplicate
// HBM/L3 delivery. 16 waves in a 4x4 grid, each wave 64x64 -> acc[2][2]
// (64 AGPR + ~64 arch VGPR = 128 @ 4 waves/SIMD: round-1-proven no-spill
// profile; the round-2 acc[2][4] variant spilled 144 dw/thread/chunk ->
// 1.2 GB of scratch writes). Grid (KC_, B_) = 256 blocks = 1 block/CU.
__global__ __launch_bounds__(1024, 4) void k_gram(
    const float* __restrict__ src, const float* __restrict__ tgt,
    float* __restrict__ partial, float* __restrict__ tot,
    float* __restrict__ sq) {
  __shared__ unsigned short lds[2 * LDSBUF];  // 72 KB
  __shared__ float red[16];
  const int kc  = blockIdx.x;
  const int b   = blockIdx.y;
  const int tid = threadIdx.x;
  const int l   = tid & 63;
  const int w   = tid >> 6;            // wave 0..15
  const int wr  = w >> 2;              // 0..3 (64-row group)
  const int wc  = w & 3;               // 0..3 (64-col group)

  // staging: thread owns column n_s, granules g and g+4 (4 threads/column
  // cover all 8 granules = BK=64 in ONE 16-reg batch).
  const int n_s = tid & 255;
  const int g   = tid >> 8;            // 0..3
  const float* colbase = (n_s < S_)
      ? (src + (size_t)b * D_ * S_ + n_s)
      : (tgt + (size_t)b * D_ * S_ + (n_s - S_));
  const float* pA = colbase + (size_t)kc * KPB * S_;

  float ld[16];
  floatx16 acc[2][2];
  #pragma unroll
  for (int i = 0; i < 2; i++)
    #pragma unroll
    for (int j = 0; j < 2; j++)
      #pragma unroll
      for (int r = 0; r < 16; r++) acc[i][j][r] = 0.f;

  const int lm   = l & 31;
  const int lk   = l >> 5;             // 0/1
  const int ar   = wr * 64 + lm;       // A rows (sub adds 32)
  const int bcol = wc * 64 + lm;       // B cols (sub adds 32)

  #define LOADH(ch)                                                    \
    do {                                                               \
      const float* q = pA + (size_t)(ch) * BK * S_;                    \
      _Pragma("unroll")                                                \
      for (int j = 0; j < 8; j++) {                                    \
        ld[j]     = q[(size_t)(g * 8 + j) * S_];                       \
        ld[8 + j] = q[(size_t)((g + 4) * 8 + j) * S_];                 \
      }                                                                \
    } while (0)

  #define WRITEH(buf)                                                  \
    do {                                                               \
      uint4 wa, wb;                                                    \
      wa.x = pk2(ld[0],  ld[1]);                                       \
      wa.y = pk2(ld[2],  ld[3]);                                       \
      wa.z = pk2(ld[4],  ld[5]);                                       \
      wa.w = pk2(ld[6],  ld[7]);                                       \
      wb.x = pk2(ld[8],  ld[9]);                                       \
      wb.y = pk2(ld[10], ld[11]);                                      \
      wb.z = pk2(ld[12], ld[13]);                                      \
      wb.w = pk2(ld[14], ld[15]);                                      \
      const int base_ = (buf) * LDSBUF;                                \
      *(uint4*)&lds[base_ + swz(n_s, g)]     = wa;                     \
      *(uint4*)&lds[base_ + swz(n_s, g + 4)] = wb;                     \
    } while (0)

  #define MFMAH(buf, k0)                                               \
    do {                                                               \
      const unsigned short* L = &lds[(buf) * LDSBUF];                  \
      _Pragma("unroll")                                                \
      for (int ks = (k0); ks < (k0) + 2; ks++) {                       \
        const int gg = ks * 2 + lk;                                    \
        short8 a0 = *(const short8*)&L[swz(ar,        gg)];            \
        short8 a1 = *(const short8*)&L[swz(ar + 32,   gg)];            \
        short8 b0 = *(const short8*)&L[swz(bcol,      gg)];            \
        short8 b1 = *(const short8*)&L[swz(bcol + 32, gg)];            \
        acc[0][0] = __builtin_amdgcn_mfma_f32_32x32x16_bf16(a0, b0, acc[0][0], 0, 0, 0); \
        acc[0][1] = __builtin_amdgcn_mfma_f32_32x32x16_bf16(a0, b1, acc[0][1], 0, 0, 0); \
        acc[1][0] = __builtin_amdgcn_mfma_f32_32x32x16_bf16(a1, b0, acc[1][0], 0, 0, 0); \
        acc[1][1] = __builtin_amdgcn_mfma_f32_32x32x16_bf16(a1, b1, acc[1][1], 0, 0, 0); \
      }                                                                \
    } while (0)

  // distance-2 pipeline: ld always holds chunk ch+1 at loop top, so the
  // vmcnt wait in WRITEH is covered by ~16 wave-MFMAs x 4 waves/SIMD.
  LOADH(0);
  WRITEH(0);
  LOADH(1);
  __syncthreads();
  for (int ch = 0; ch < NCH - 1; ch++) {
    MFMAH(ch & 1, 0);          // 8 MFMA on current chunk
    WRITEH((ch + 1) & 1);      // stage chunk ch+1 (loaded last iteration)
    if (ch + 2 < NCH) LOADH(ch + 2);  // uniform branch, no divergence
    MFMAH(ch & 1, 2);          // 8 MFMA
    __syncthreads();
  }
  MFMAH((NCH - 1) & 1, 0);
  MFMAH((NCH - 1) & 1, 2);

  // ---- epilogue: store full tile (plain stores, 2x128B per instr) ----
  float* gb = partial + ((size_t)kc * B_ + b) * TILE_;
  #pragma unroll
  for (int i = 0; i < 2; i++)
    #pragma unroll
    for (int j = 0; j < 2; j++)
      #pragma unroll
      for (int r = 0; r < 16; r++) {
        const int row = (r & 3) + 8 * (r >> 2) + 4 * lk;  // verified C/D layout
        const int nr  = wr * 64 + i * 32 + row;
        const int nc  = wc * 64 + j * 32 + (l & 31);
        gb[nr * N_ + nc] = acc[i][j][r];
      }

  // ---- tot[b]: block-level sum of this tile ----
  float s = 0.f;
  #pragma unroll
  for (int i = 0; i < 2; i++)
    #pragma unroll
    for (int j = 0; j < 2; j++)
      #pragma unroll
      for (int r = 0; r < 16; r++) s += acc[i][j][r];
  for (int off = 32; off; off >>= 1) s += __shfl_down(s, off);
  if (l == 0) red[w] = s;
  __syncthreads();
  if (tid == 0) {
    float T = 0.f;
    #pragma unroll
    for (int i = 0; i < 16; i++) T += red[i];
    atomicAdd(&tot[b], T);
  }

  // ---- sq[b][c]: diagonal contributions (waves with wr == wc) ----
  if (wr == wc && lk == ((l >> 2) & 1)) {
    const int c = l & 31;
    const int r = (c >> 3) * 4 + (c & 3);   // reg holding row==col
    #pragma unroll
    for (int i = 0; i < 2; i++)
      atomicAdd(&sq[b * N_ + wr * 64 + i * 32 + c], acc[i][i][r]);
  }
  #undef LOADH
  #undef WRITEH
  #undef MFMAH
}

// Sum 4 partials inline, reconstruct L2, 5-kernel exp with quadrant signs.
// 512 blocks (8 row-chunks x 64 batches, 2 blocks/CU), float4 loads.
__global__ __launch_bounds__(512, 4) void k_exp(
    const float* __restrict__ partial, const float* __restrict__ tot,
    const float* __restrict__ sq, float* __restrict__ out) {
  __shared__ float sqs[N_];
  __shared__ float red[8];
  __shared__ float bws;
  const int rc = blockIdx.x;           // 0..7: 32-row chunk
  const int b  = blockIdx.y;
  const int t  = threadIdx.x;          // 512
  const int cg = t & 63;               // col group (x4)
  const int rg = t >> 6;               // 0..7: 4-row group

  if (t < N_) sqs[t] = sq[b * N_ + t];
  __syncthreads();
  if (t < N_) {
    float v = sqs[t];
    for (int off = 32; off; off >>= 1) v += __shfl_down(v, off);
    if ((t & 63) == 0) red[t >> 6] = v;
  }
  __syncthreads();
  if (t == 0) {
    float ssq = red[0] + red[1] + red[2] + red[3];
    float SL2 = 2.f * (float)N_ * ssq - 2.f * tot[b];
    bws = SL2 / (float)(N_ * N_ - N_) * 0.25f;  // / kernel_mul^(num//2)
  }
  __syncthreads();

  const float bwv = bws;
  float nb[5];
  #pragma unroll
  for (int k = 0; k < 5; k++)
    nb[k] = -1.4426950408889634f / (bwv * (float)(1 << k));

  const int c4 = cg * 4;
  const float4 sqc = *(const float4*)&sqs[c4];
  const float sgn = ((rc < 4) == (cg < 32)) ? 1.f : -1.f;  // quadrant sign
  const float* p0 = partial + (size_t)b * TILE_;

  float accv = 0.f;
  #pragma unroll
  for (int r = 0; r < 4; r++) {
    const int row = rc * 32 + rg * 4 + r;
    const float4 g0 = *(const float4*)&p0[row * N_ + c4];
    const float4 g1 = *(const float4*)&p0[(size_t)1 * B_ * TILE_ + row * N_ + c4];
    const float4 g2 = *(const float4*)&p0[(size_t)2 * B_ * TILE_ + row * N_ + c4];
    const float4 g3 = *(const float4*)&p0[(size_t)3 * B_ * TILE_ + row * N_ + c4];
    const float sr = sqs[row];
    float4 L2;
    L2.x = sr + sqc.x - 2.f * (g0.x + g1.x + g2.x + g3.x);
    L2.y = sr + sqc.y - 2.f * (g0.y + g1.y + g2.y + g3.y);
    L2.z = sr + sqc.z - 2.f * (g0.z + g1.z + g2.z + g3.z);
    L2.w = sr + sqc.w - 2.f * (g0.w + g1.w + g2.w + g3.w);
    #pragma unroll
    for (int k = 0; k < 5; k++) {
      accv += exp2f(L2.x * nb[k]) + exp2f(L2.y * nb[k])
            + exp2f(L2.z * nb[k]) + exp2f(L2.w * nb[k]);
    }
  }
  accv *= sgn;
  for (int off = 32; off; off >>= 1) accv += __shfl_down(accv, off);
  __syncthreads();  // red[] reuse safe (t==0 consumed it before bws barrier)
  if ((t & 63) == 0) red[t >> 6] = accv;
  __syncthreads();
  if (t == 0) {
    float s2 = red[0] + red[1] + red[2] + red[3]
             + red[4] + red[5] + red[6] + red[7];
    atomicAdd(out, s2 * (1.0f / (64.f * 16384.f)));  // / (B * S*S)
  }
}

extern "C" void kernel_launch(void* const* d_in, const int* in_sizes, int n_in,
                              void* d_out, int out_size, void* d_ws, size_t ws_size,
                              hipStream_t stream) {
  const float* src = (const float*)d_in[0];
  const float* tgt = (const float*)d_in[1];
  const size_t partial_bytes = (size_t)KC_ * B_ * TILE_ * sizeof(float);  // 67 MB
  float* partial = (float*)d_ws;
  float* tot     = (float*)((char*)d_ws + partial_bytes);         // 64 floats
  float* sq      = tot + B_;                                      // 64*256 floats
  hipMemsetAsync(tot, 0, (B_ + B_ * N_) * sizeof(float), stream);
  hipMemsetAsync(d_out, 0, sizeof(float), stream);
  k_gram<<<dim3(KC_, B_), 1024, 0, stream>>>(src, tgt, partial, tot, sq);
  k_exp<<<dim3(8, B_), 512, 0, stream>>>(partial, tot, sq, (float*)d_out);
}